// Round 4
// baseline (11563.007 us; speedup 1.0000x reference)
//
#include <hip/hip_runtime.h>
#include <hip/hip_bf16.h>
#include <stdint.h>

#define T_STEPS 512
#define BATCH   64
#define IN_DIM  512
#define H_DIM   1024
#define KDIM    1536          // H + IN
#define NWG     128
#define NTHREADS 512
#define KSTEPS  48            // KDIM / 32
#define SLICE_KSTEPS 6        // KSTEPS / 8 waves

// LDS layout
#define WLDS_BYTES (2*48*64*16)            // 98304: B-frags [nt][ks][lane][16B]
#define SMP_BYTES  (4*2048*4)              // 32768: 4 partial regions [8 tiles][64 lanes][f32x4]
#define SMZ_BYTES  (64*33*4)               // 8448
#define LDS_TOTAL  (WLDS_BYTES + SMP_BYTES + SMZ_BYTES)   // 139520 <= 160K

// ws layout (bytes)
#define WS_FLAGS 0              // 128 flags, 256B stride -> 32768
#define WS_HB    32768          // ping-pong h, 2*64*1024 bf16 -> 262144
#define WS_XB    294912         // x as bf16, 512*64*512*2 -> 33554432
#define WS_WPK   33849344       // packed weights 12582912; total ~46.4 MB

typedef float  f32x4  __attribute__((ext_vector_type(4)));
typedef short  short8 __attribute__((ext_vector_type(8)));
typedef __bf16 bf16x8 __attribute__((ext_vector_type(8)));

__device__ __forceinline__ short f2bf(float f) {
    union { float f; unsigned u; } x; x.f = f;
    unsigned r = (x.u + 0x7fffu + ((x.u >> 16) & 1u)) >> 16;
    return (short)r;
}

// W[g] fp32 [1024][1536] -> per-WG B-fragment order:
// wg=j>>3, nt=g>>1, nidx=(g&1)*8+(j&7), ks=k>>5, grp=(k&31)>>3, u=k&7
// dst slot ((wg*2+nt)*48+ks), lane grp*16+nidx holds 8 shorts along k.
__global__ __launch_bounds__(256) void pack_w_kernel(const float* __restrict__ W,
                                                     short* __restrict__ Wpk, int g) {
    int e = blockIdx.x * 256 + threadIdx.x;      // e < 1024*1536
    int j = e / KDIM, k = e - j * KDIM;
    short v = f2bf(W[e]);
    int wg = j >> 3, nt = g >> 1, nidx = (g & 1) * 8 + (j & 7);
    int ks = k >> 5, grp = (k & 31) >> 3, u = k & 7;
    size_t dst = ((size_t)((wg * 2 + nt) * 48 + ks) * 64 + grp * 16 + nidx) * 8 + u;
    Wpk[dst] = v;
}

__global__ __launch_bounds__(256) void xconv_kernel(const float* __restrict__ x,
                                                    short* __restrict__ xb) {
    size_t e = ((size_t)blockIdx.x * 256 + threadIdx.x) * 8;   // 8192 blocks cover 16.7M
    f32x4 v0 = *reinterpret_cast<const f32x4*>(x + e);
    f32x4 v1 = *reinterpret_cast<const f32x4*>(x + e + 4);
    short8 o;
    #pragma unroll
    for (int u = 0; u < 4; ++u) { o[u] = f2bf(v0[u]); o[4 + u] = f2bf(v1[u]); }
    *reinterpret_cast<short8*>(xb + e) = o;
}

__global__ __launch_bounds__(256) void init_state_kernel(int* flags, int* hb_i) {
    int e = blockIdx.x * 256 + threadIdx.x;
    if (e < 8192) flags[e] = 0;                 // 32 KB flag region
    if (e < 65536) hb_i[e] = 0;                 // both h buffers (262144 B as ints)
}

__device__ __forceinline__ void grid_barrier(int* flags, int wg, int gen) {
    __syncthreads();   // all this-WG writes issued & drained before publish
    const int tid = threadIdx.x;
    if (tid == 0) {
        __hip_atomic_store(&flags[wg * 64], gen, __ATOMIC_RELEASE, __HIP_MEMORY_SCOPE_AGENT);
    }
    if (tid < NWG) {
        // ACQUIRE at agent scope: guarantees the load reaches the cross-XCD
        // coherence point each poll (a relaxed load hitting a stale per-XCD L2
        // line forever would be a hang).
        while (__hip_atomic_load(&flags[tid * 64], __ATOMIC_ACQUIRE,
                                 __HIP_MEMORY_SCOPE_AGENT) < gen) { }
    }
    __syncthreads();
    __builtin_amdgcn_fence(__ATOMIC_ACQUIRE, "agent");   // bulk-data visibility (h ping-pong)
}

extern "C" __global__ void __launch_bounds__(NTHREADS)
lstm_persistent(const short* __restrict__ Wpk, const short* __restrict__ xb,
                short* __restrict__ hb, float* __restrict__ out,
                const float* __restrict__ bf_, const float* __restrict__ bi_,
                const float* __restrict__ bc_, const float* __restrict__ bo_,
                int* __restrict__ flags)
{
    extern __shared__ char lds[];
    short* Wlds = (short*)lds;                               // [2][48][64][8]
    float* smP  = (float*)(lds + WLDS_BYTES);                // 4 regions x 2048 f32
    float* smZ  = (float*)(lds + WLDS_BYTES + SMP_BYTES);    // [64][33]

    const int tid = threadIdx.x, w = tid >> 6, lane = tid & 63;
    const int wg = blockIdx.x;
    const int r = lane & 15, hi = lane >> 4;

    // ---- weights -> LDS, once ----
    const short* wsrc = Wpk + (size_t)wg * (2 * 48 * 512);
    #pragma unroll
    for (int q = 0; q < 12; ++q) {
        int sl = q * 512 + tid;                              // < 6144 16B-slots
        *reinterpret_cast<short8*>(Wlds + sl * 8) =
            *reinterpret_cast<const short8*>(wsrc + (size_t)sl * 8);
    }
    // ---- per-thread output element (eb,ej), bias + c state in regs ----
    const int eb = tid >> 3, ej = tid & 7;
    const int j_out = wg * 8 + ej;
    const float bfv = bf_[j_out], biv = bi_[j_out], bcv = bc_[j_out], bov = bo_[j_out];
    float creg = 0.f;
    __syncthreads();

    for (int t = 0; t < T_STEPS; ++t) {
        const short* hcur = hb + (size_t)(t & 1) * (BATCH * H_DIM);
        f32x4 acc[4][2];
        #pragma unroll
        for (int mt = 0; mt < 4; ++mt)
            #pragma unroll
            for (int nt = 0; nt < 2; ++nt) acc[mt][nt] = (f32x4){0.f, 0.f, 0.f, 0.f};

        // ---- my K-slice: 6 ksteps, full 64x32 block (A global-direct, B from LDS) ----
        #pragma unroll
        for (int s = 0; s < SLICE_KSTEPS; ++s) {
            const int ks = w * SLICE_KSTEPS + s;
            const short* asrc; int rs;
            if (ks < 32) { asrc = hcur + ks * 32 + hi * 8;                         rs = H_DIM; }
            else { asrc = xb + (size_t)t * (BATCH * IN_DIM) + (ks - 32) * 32 + hi * 8; rs = IN_DIM; }
            short8 a[4];
            #pragma unroll
            for (int mt = 0; mt < 4; ++mt)
                a[mt] = *reinterpret_cast<const short8*>(asrc + (size_t)(mt * 16 + r) * rs);
            short8 b0 = *reinterpret_cast<const short8*>(Wlds + ((size_t)(0 * 48 + ks) * 64 + lane) * 8);
            short8 b1 = *reinterpret_cast<const short8*>(Wlds + ((size_t)(1 * 48 + ks) * 64 + lane) * 8);
            #pragma unroll
            for (int mt = 0; mt < 4; ++mt) {
                acc[mt][0] = __builtin_amdgcn_mfma_f32_16x16x32_bf16(
                    __builtin_bit_cast(bf16x8, a[mt]), __builtin_bit_cast(bf16x8, b0), acc[mt][0], 0, 0, 0);
                acc[mt][1] = __builtin_amdgcn_mfma_f32_16x16x32_bf16(
                    __builtin_bit_cast(bf16x8, a[mt]), __builtin_bit_cast(bf16x8, b1), acc[mt][1], 0, 0, 0);
            }
        }

        // ---- 8 -> 1 K-slice reduction tree through smP ----
        if (w >= 4) {
            float* p = smP + (w - 4) * 2048;
            #pragma unroll
            for (int mt = 0; mt < 4; ++mt)
                #pragma unroll
                for (int nt = 0; nt < 2; ++nt)
                    *reinterpret_cast<f32x4*>(p + (mt * 2 + nt) * 256 + lane * 4) = acc[mt][nt];
        }
        __syncthreads();
        if (w < 4) {
            float* p = smP + w * 2048;
            #pragma unroll
            for (int mt = 0; mt < 4; ++mt)
                #pragma unroll
                for (int nt = 0; nt < 2; ++nt)
                    acc[mt][nt] += *reinterpret_cast<const f32x4*>(p + (mt * 2 + nt) * 256 + lane * 4);
        }
        if (w == 2 || w == 3) {
            float* p = smP + w * 2048;                       // own region (read above)
            #pragma unroll
            for (int mt = 0; mt < 4; ++mt)
                #pragma unroll
                for (int nt = 0; nt < 2; ++nt)
                    *reinterpret_cast<f32x4*>(p + (mt * 2 + nt) * 256 + lane * 4) = acc[mt][nt];
        }
        __syncthreads();
        if (w < 2) {
            float* p = smP + (w + 2) * 2048;
            #pragma unroll
            for (int mt = 0; mt < 4; ++mt)
                #pragma unroll
                for (int nt = 0; nt < 2; ++nt)
                    acc[mt][nt] += *reinterpret_cast<const f32x4*>(p + (mt * 2 + nt) * 256 + lane * 4);
        }
        if (w == 1) {
            float* p = smP + 1 * 2048;                       // own region
            #pragma unroll
            for (int mt = 0; mt < 4; ++mt)
                #pragma unroll
                for (int nt = 0; nt < 2; ++nt)
                    *reinterpret_cast<f32x4*>(p + (mt * 2 + nt) * 256 + lane * 4) = acc[mt][nt];
        }
        __syncthreads();
        if (w == 0) {
            float* p = smP + 1 * 2048;
            #pragma unroll
            for (int mt = 0; mt < 4; ++mt)
                #pragma unroll
                for (int nt = 0; nt < 2; ++nt) {
                    acc[mt][nt] += *reinterpret_cast<const f32x4*>(p + (mt * 2 + nt) * 256 + lane * 4);
                    #pragma unroll
                    for (int i = 0; i < 4; ++i)   // C layout: col=lane&15, row=(lane>>4)*4+i
                        smZ[(mt * 16 + hi * 4 + i) * 33 + nt * 16 + r] = acc[mt][nt][i];
                }
        }
        __syncthreads();

        // ---- elementwise: one output element per thread ----
        float zf = smZ[eb * 33 +  0 + ej] + bfv;
        float zi = smZ[eb * 33 +  8 + ej] + biv;
        float zc = smZ[eb * 33 + 16 + ej] + bcv;
        float zo = smZ[eb * 33 + 24 + ej] + bov;
        float fg  = 1.f / (1.f + __expf(-zf));
        float ig  = 1.f / (1.f + __expf(-zi));
        float cg_ = 2.f / (1.f + __expf(-2.f * zc)) - 1.f;
        float og  = 1.f / (1.f + __expf(-zo));
        creg = fg * creg + ig * cg_;
        float nh = og * (2.f / (1.f + __expf(-2.f * creg)) - 1.f);
        short* hnext = hb + (size_t)((t + 1) & 1) * (BATCH * H_DIM);
        hnext[eb * H_DIM + j_out] = f2bf(nh);
        out[(size_t)t * (BATCH * H_DIM) + eb * H_DIM + j_out] = nh;

        grid_barrier(flags, wg, t + 1);
    }
}

extern "C" void kernel_launch(void* const* d_in, const int* in_sizes, int n_in,
                              void* d_out, int out_size, void* d_ws, size_t ws_size,
                              hipStream_t stream) {
    const float* x   = (const float*)d_in[0];
    const float* Wf  = (const float*)d_in[1];
    const float* Wi  = (const float*)d_in[2];
    const float* Wc  = (const float*)d_in[3];
    const float* Wo  = (const float*)d_in[4];
    const float* bf_ = (const float*)d_in[5];
    const float* bi_ = (const float*)d_in[6];
    const float* bc_ = (const float*)d_in[7];
    const float* bo_ = (const float*)d_in[8];
    float* out = (float*)d_out;

    char*  ws    = (char*)d_ws;
    int*   flags = (int*)(ws + WS_FLAGS);
    short* hbuf  = (short*)(ws + WS_HB);
    short* xb    = (short*)(ws + WS_XB);
    short* Wpk   = (short*)(ws + WS_WPK);

    // Unconditional (no static guard — harness requires deterministic calls).
    // Host-side attribute set; not a stream op, safe under graph capture.
    hipFuncSetAttribute((const void*)lstm_persistent,
                        hipFuncAttributeMaxDynamicSharedMemorySize, LDS_TOTAL);

    const float* Ws[4] = {Wf, Wi, Wc, Wo};
    for (int g = 0; g < 4; ++g)
        pack_w_kernel<<<(H_DIM * KDIM) / 256, 256, 0, stream>>>(Ws[g], Wpk, g);
    xconv_kernel<<<(T_STEPS * BATCH * IN_DIM) / (256 * 8), 256, 0, stream>>>(x, xb);
    init_state_kernel<<<256, 256, 0, stream>>>(flags, (int*)hbuf);

    const short* Wpk_c = Wpk; const short* xb_c = xb;
    void* args[] = {(void*)&Wpk_c, (void*)&xb_c, (void*)&hbuf, (void*)&out,
                    (void*)&bf_, (void*)&bi_, (void*)&bc_, (void*)&bo_, (void*)&flags};
    hipLaunchCooperativeKernel((const void*)lstm_persistent, dim3(NWG), dim3(NTHREADS),
                               args, LDS_TOTAL, stream);
}

// Round 6
// 9773.380 us; speedup vs baseline: 1.1831x; 1.1831x over previous
//
#include <hip/hip_runtime.h>
#include <hip/hip_bf16.h>
#include <stdint.h>

#define T_STEPS 512
#define BATCH   64
#define IN_DIM  512
#define H_DIM   1024
#define KDIM    1536          // H + IN
#define NWG     128
#define NTHREADS 512

// LDS layout
#define WLDS_BYTES (2*48*64*16)            // 98304: B-frags [nt][ks][lane][16B]
#define SMP_BYTES  (4*2048*4)              // 32768: 4 partial regions
#define SMZ_BYTES  (64*33*4)               // 8448
#define LDS_TOTAL  (WLDS_BYTES + SMP_BYTES + SMZ_BYTES)   // 139520 <= 160K

// ws layout (bytes)
#define WS_SYNC  0              // root@int0, gen@int64, grp[i]@int(128+64i); 32KB region
#define WS_HB    32768          // ping-pong h, 2*64*1024 bf16 -> 262144
#define WS_XB    294912         // x as bf16 -> 33554432
#define WS_WPK   33849344       // packed weights 12582912

typedef float  f32x4  __attribute__((ext_vector_type(4)));
typedef short  short8 __attribute__((ext_vector_type(8)));
typedef __bf16 bf16x8 __attribute__((ext_vector_type(8)));

__device__ __forceinline__ short f2bf(float f) {
    union { float f; unsigned u; } x; x.f = f;
    unsigned r = (x.u + 0x7fffu + ((x.u >> 16) & 1u)) >> 16;
    return (short)r;
}
__device__ __forceinline__ f32x4 bmfma(short8 a, short8 b, f32x4 c) {
    return __builtin_amdgcn_mfma_f32_16x16x32_bf16(
        __builtin_bit_cast(bf16x8, a), __builtin_bit_cast(bf16x8, b), c, 0, 0, 0);
}

// W[g] fp32 [1024][1536] -> per-WG B-fragment order (unchanged from passing r4).
__global__ __launch_bounds__(256) void pack_w_kernel(const float* __restrict__ W,
                                                     short* __restrict__ Wpk, int g) {
    int e = blockIdx.x * 256 + threadIdx.x;
    int j = e / KDIM, k = e - j * KDIM;
    short v = f2bf(W[e]);
    int wg = j >> 3, nt = g >> 1, nidx = (g & 1) * 8 + (j & 7);
    int ks = k >> 5, grp = (k & 31) >> 3, u = k & 7;
    size_t dst = ((size_t)((wg * 2 + nt) * 48 + ks) * 64 + grp * 16 + nidx) * 8 + u;
    Wpk[dst] = v;
}

__global__ __launch_bounds__(256) void xconv_kernel(const float* __restrict__ x,
                                                    short* __restrict__ xb) {
    size_t e = ((size_t)blockIdx.x * 256 + threadIdx.x) * 8;
    f32x4 v0 = *reinterpret_cast<const f32x4*>(x + e);
    f32x4 v1 = *reinterpret_cast<const f32x4*>(x + e + 4);
    short8 o;
    #pragma unroll
    for (int u = 0; u < 4; ++u) { o[u] = f2bf(v0[u]); o[4 + u] = f2bf(v1[u]); }
    *reinterpret_cast<short8*>(xb + e) = o;
}

__global__ __launch_bounds__(256) void init_state_kernel(int* sync, int* hb_i) {
    int e = blockIdx.x * 256 + threadIdx.x;
    if (e < 8192) sync[e] = 0;                  // root/gen/group counters
    if (e < 65536) hb_i[e] = 0;                 // both h ping-pong buffers
}

extern "C" __global__ void __launch_bounds__(NTHREADS, 2)
lstm_persistent(const short* __restrict__ Wpk, const short* __restrict__ xb,
                short* __restrict__ hb, float* __restrict__ out,
                const float* __restrict__ bf_, const float* __restrict__ bi_,
                const float* __restrict__ bc_, const float* __restrict__ bo_,
                int* __restrict__ sync)
{
    extern __shared__ char lds[];
    short* Wlds = (short*)lds;                               // [2][48][64][8]
    float* smP  = (float*)(lds + WLDS_BYTES);
    float* smZ  = (float*)(lds + WLDS_BYTES + SMP_BYTES);    // [64][33]

    const int tid = threadIdx.x, w = tid >> 6, lane = tid & 63;
    const int wg = blockIdx.x;
    const int r = lane & 15, hi = lane >> 4;
    int* root = sync;                     // monotone, 8 bumps/step
    int* gen  = sync + 64;                // published step number
    int* grpc = sync + 128 + (wg & 7) * 64;   // per-group monotone, 16 bumps/step

    // ---- weights -> LDS, once ----
    const short* wsrc = Wpk + (size_t)wg * (2 * 48 * 512);
    #pragma unroll
    for (int q = 0; q < 12; ++q) {
        int sl = q * 512 + tid;
        *reinterpret_cast<short8*>(Wlds + sl * 8) =
            *reinterpret_cast<const short8*>(wsrc + (size_t)sl * 8);
    }
    const int eb = tid >> 3, ej = tid & 7;
    const int j_out = wg * 8 + ej;
    const float bfv = bf_[j_out], biv = bi_[j_out], bcv = bc_[j_out], bov = bo_[j_out];
    float creg = 0.f;
    __syncthreads();

    f32x4 acc[4][2];
    // x-part of the GEMM for timestep tt (16 of 48 ksteps; no h dependence).
    auto x_part = [&](int tt) {
        const short* xt = xb + (size_t)tt * (BATCH * IN_DIM);
        short8 ax[2][4];
        #pragma unroll
        for (int s = 0; s < 2; ++s) {
            const int kx = w * 2 + s;                         // 0..15
            const short* asrc = xt + kx * 32 + hi * 8;
            #pragma unroll
            for (int mt = 0; mt < 4; ++mt)
                ax[s][mt] = *reinterpret_cast<const short8*>(asrc + (size_t)(mt * 16 + r) * IN_DIM);
        }
        #pragma unroll
        for (int s = 0; s < 2; ++s) {
            const int ks = 32 + w * 2 + s;
            short8 b0 = *reinterpret_cast<const short8*>(Wlds + ((size_t)(0 * 48 + ks) * 64 + lane) * 8);
            short8 b1 = *reinterpret_cast<const short8*>(Wlds + ((size_t)(1 * 48 + ks) * 64 + lane) * 8);
            #pragma unroll
            for (int mt = 0; mt < 4; ++mt) {
                acc[mt][0] = bmfma(ax[s][mt], b0, acc[mt][0]);
                acc[mt][1] = bmfma(ax[s][mt], b1, acc[mt][1]);
            }
        }
    };

    #pragma unroll
    for (int mt = 0; mt < 4; ++mt)
        #pragma unroll
        for (int nt = 0; nt < 2; ++nt) acc[mt][nt] = (f32x4){0.f, 0.f, 0.f, 0.f};
    x_part(0);   // prologue

    for (int t = 0; t < T_STEPS; ++t) {
        // ---- wait: h(t) published (skip t=0, zeros from init kernel) ----
        if (t > 0) {
            if (tid == 0) {
                while (__hip_atomic_load(gen, __ATOMIC_RELAXED, __HIP_MEMORY_SCOPE_AGENT) < t)
                    __builtin_amdgcn_s_sleep(2);
            }
            __syncthreads();
            __builtin_amdgcn_fence(__ATOMIC_ACQUIRE, "agent");
        }

        // ---- h-part: 4 ksteps/wave, all 16 A-frags prefetched ----
        const short* hcur = hb + (size_t)(t & 1) * (BATCH * H_DIM);
        short8 a[4][4];
        #pragma unroll
        for (int s = 0; s < 4; ++s) {
            const int ks = w * 4 + s;                         // 0..31
            const short* asrc = hcur + ks * 32 + hi * 8;
            #pragma unroll
            for (int mt = 0; mt < 4; ++mt)
                a[s][mt] = *reinterpret_cast<const short8*>(asrc + (size_t)(mt * 16 + r) * H_DIM);
        }
        #pragma unroll
        for (int s = 0; s < 4; ++s) {
            const int ks = w * 4 + s;
            short8 b0 = *reinterpret_cast<const short8*>(Wlds + ((size_t)(0 * 48 + ks) * 64 + lane) * 8);
            short8 b1 = *reinterpret_cast<const short8*>(Wlds + ((size_t)(1 * 48 + ks) * 64 + lane) * 8);
            #pragma unroll
            for (int mt = 0; mt < 4; ++mt) {
                acc[mt][0] = bmfma(a[s][mt], b0, acc[mt][0]);
                acc[mt][1] = bmfma(a[s][mt], b1, acc[mt][1]);
            }
        }

        // ---- 8 -> 1 K-slice reduction tree ----
        if (w >= 4) {
            float* p = smP + (w - 4) * 2048;
            #pragma unroll
            for (int mt = 0; mt < 4; ++mt)
                #pragma unroll
                for (int nt = 0; nt < 2; ++nt)
                    *reinterpret_cast<f32x4*>(p + (mt * 2 + nt) * 256 + lane * 4) = acc[mt][nt];
        }
        __syncthreads();
        if (w < 4) {
            float* p = smP + w * 2048;
            #pragma unroll
            for (int mt = 0; mt < 4; ++mt)
                #pragma unroll
                for (int nt = 0; nt < 2; ++nt)
                    acc[mt][nt] += *reinterpret_cast<const f32x4*>(p + (mt * 2 + nt) * 256 + lane * 4);
        }
        if (w == 2 || w == 3) {
            float* p = smP + w * 2048;
            #pragma unroll
            for (int mt = 0; mt < 4; ++mt)
                #pragma unroll
                for (int nt = 0; nt < 2; ++nt)
                    *reinterpret_cast<f32x4*>(p + (mt * 2 + nt) * 256 + lane * 4) = acc[mt][nt];
        }
        __syncthreads();
        if (w < 2) {
            float* p = smP + (w + 2) * 2048;
            #pragma unroll
            for (int mt = 0; mt < 4; ++mt)
                #pragma unroll
                for (int nt = 0; nt < 2; ++nt)
                    acc[mt][nt] += *reinterpret_cast<const f32x4*>(p + (mt * 2 + nt) * 256 + lane * 4);
        }
        if (w == 1) {
            float* p = smP + 1 * 2048;
            #pragma unroll
            for (int mt = 0; mt < 4; ++mt)
                #pragma unroll
                for (int nt = 0; nt < 2; ++nt)
                    *reinterpret_cast<f32x4*>(p + (mt * 2 + nt) * 256 + lane * 4) = acc[mt][nt];
        }
        __syncthreads();
        if (w == 0) {
            float* p = smP + 1 * 2048;
            #pragma unroll
            for (int mt = 0; mt < 4; ++mt)
                #pragma unroll
                for (int nt = 0; nt < 2; ++nt) {
                    acc[mt][nt] += *reinterpret_cast<const f32x4*>(p + (mt * 2 + nt) * 256 + lane * 4);
                    #pragma unroll
                    for (int i = 0; i < 4; ++i)   // C layout: col=lane&15, row=(lane>>4)*4+i
                        smZ[(mt * 16 + hi * 4 + i) * 33 + nt * 16 + r] = acc[mt][nt][i];
                }
        }
        __syncthreads();

        // ---- elementwise (one output/thread); h plain store, out NT store ----
        float zf = smZ[eb * 33 +  0 + ej] + bfv;
        float zi = smZ[eb * 33 +  8 + ej] + biv;
        float zc = smZ[eb * 33 + 16 + ej] + bcv;
        float zo = smZ[eb * 33 + 24 + ej] + bov;
        float fg  = 1.f / (1.f + __expf(-zf));
        float ig  = 1.f / (1.f + __expf(-zi));
        float cg_ = 2.f / (1.f + __expf(-2.f * zc)) - 1.f;
        float og  = 1.f / (1.f + __expf(-zo));
        creg = fg * creg + ig * cg_;
        float nh = og * (2.f / (1.f + __expf(-2.f * creg)) - 1.f);
        short* hnext = hb + (size_t)((t + 1) & 1) * (BATCH * H_DIM);
        hnext[eb * H_DIM + j_out] = f2bf(nh);
        __builtin_nontemporal_store(nh, out + (size_t)t * (BATCH * H_DIM) + eb * H_DIM + j_out);

        // ---- arrive (split-phase): release h(t+1), bump tree, maybe publish ----
        __syncthreads();   // all waves' stores vmcnt-drained into L2
        if (w == 0) {
            __builtin_amdgcn_fence(__ATOMIC_RELEASE, "agent");   // wb dirty L2 (small set)
            if (lane == 0) {
                int old = __hip_atomic_fetch_add(grpc, 1, __ATOMIC_RELAXED, __HIP_MEMORY_SCOPE_AGENT);
                if (old == 16 * (t + 1) - 1) {                   // last of my 16-WG group
                    int o2 = __hip_atomic_fetch_add(root, 1, __ATOMIC_RELAXED, __HIP_MEMORY_SCOPE_AGENT);
                    if (o2 == 8 * (t + 1) - 1)                   // last group
                        __hip_atomic_store(gen, t + 1, __ATOMIC_RELEASE, __HIP_MEMORY_SCOPE_AGENT);
                }
            }
        }

        // ---- overlap: x-part of step t+1 while others arrive ----
        #pragma unroll
        for (int mt = 0; mt < 4; ++mt)
            #pragma unroll
            for (int nt = 0; nt < 2; ++nt) acc[mt][nt] = (f32x4){0.f, 0.f, 0.f, 0.f};
        if (t + 1 < T_STEPS) x_part(t + 1);
    }
}

extern "C" void kernel_launch(void* const* d_in, const int* in_sizes, int n_in,
                              void* d_out, int out_size, void* d_ws, size_t ws_size,
                              hipStream_t stream) {
    const float* x   = (const float*)d_in[0];
    const float* Wf  = (const float*)d_in[1];
    const float* Wi  = (const float*)d_in[2];
    const float* Wc  = (const float*)d_in[3];
    const float* Wo  = (const float*)d_in[4];
    const float* bf_ = (const float*)d_in[5];
    const float* bi_ = (const float*)d_in[6];
    const float* bc_ = (const float*)d_in[7];
    const float* bo_ = (const float*)d_in[8];
    float* out = (float*)d_out;

    char*  ws    = (char*)d_ws;
    int*   syncp = (int*)(ws + WS_SYNC);
    short* hbuf  = (short*)(ws + WS_HB);
    short* xb    = (short*)(ws + WS_XB);
    short* Wpk   = (short*)(ws + WS_WPK);

    hipFuncSetAttribute((const void*)lstm_persistent,
                        hipFuncAttributeMaxDynamicSharedMemorySize, LDS_TOTAL);

    const float* Ws[4] = {Wf, Wi, Wc, Wo};
    for (int g = 0; g < 4; ++g)
        pack_w_kernel<<<(H_DIM * KDIM) / 256, 256, 0, stream>>>(Ws[g], Wpk, g);
    xconv_kernel<<<(T_STEPS * BATCH * IN_DIM) / (256 * 8), 256, 0, stream>>>(x, xb);
    init_state_kernel<<<256, 256, 0, stream>>>(syncp, (int*)hbuf);

    const short* Wpk_c = Wpk; const short* xb_c = xb;
    void* args[] = {(void*)&Wpk_c, (void*)&xb_c, (void*)&hbuf, (void*)&out,
                    (void*)&bf_, (void*)&bi_, (void*)&bc_, (void*)&bo_, (void*)&syncp};
    hipLaunchCooperativeKernel((const void*)lstm_persistent, dim3(NWG), dim3(NTHREADS),
                               args, LDS_TOTAL, stream);
}

// Round 7
// 7292.409 us; speedup vs baseline: 1.5856x; 1.3402x over previous
//
#include <hip/hip_runtime.h>
#include <hip/hip_bf16.h>
#include <stdint.h>

#define T_STEPS 512
#define BATCH   64
#define IN_DIM  512
#define H_DIM   1024
#define KDIM    1536
#define NWG     256
#define NTHREADS 256

// ws layout (bytes). sync ints: root@0, grpc[g]@128+64g (g<16), mirror[m]@2048+64m (m<16)
#define WS_SYNC 0
#define WS_HB   32768           // ping-pong h, 2*64*1024 bf16 = 262144 B
#define WS_XB   294912          // x as bf16 = 33554432 B
#define WS_WPK  33849344        // packed weights 12582912 B

typedef float  f32x4  __attribute__((ext_vector_type(4)));
typedef short  short8 __attribute__((ext_vector_type(8)));
typedef __bf16 bf16x8 __attribute__((ext_vector_type(8)));

__device__ __forceinline__ short f2bf(float f) {
    union { float f; unsigned u; } x; x.f = f;
    unsigned r = (x.u + 0x7fffu + ((x.u >> 16) & 1u)) >> 16;
    return (short)r;
}
__device__ __forceinline__ f32x4 bmfma(short8 a, short8 b, f32x4 c) {
    return __builtin_amdgcn_mfma_f32_16x16x32_bf16(
        __builtin_bit_cast(bf16x8, a), __builtin_bit_cast(bf16x8, b), c, 0, 0, 0);
}

// W[g] fp32 [1024][1536] -> per-WG(4 h-cols) B-frag order:
// Wpk[((wg*48+ks)*64 + hi*16 + (g*4+cj))*8 + u] = bf16(W[g][wg*4+cj][ks*32+hi*8+u])
__global__ __launch_bounds__(256) void pack_w_kernel(const float* __restrict__ W,
                                                     short* __restrict__ Wpk, int g) {
    int e = blockIdx.x * 256 + threadIdx.x;       // < 1024*1536
    int j = e / KDIM, k = e - j * KDIM;
    int wg = j >> 2, cj = j & 3, zc = g * 4 + cj;
    int ks = k >> 5, h2 = (k & 31) >> 3, u = k & 7;
    Wpk[(((size_t)(wg * 48 + ks) * 64) + h2 * 16 + zc) * 8 + u] = f2bf(W[e]);
}

__global__ __launch_bounds__(256) void xconv_kernel(const float* __restrict__ x,
                                                    short* __restrict__ xb) {
    size_t e = ((size_t)blockIdx.x * 256 + threadIdx.x) * 8;
    f32x4 v0 = *reinterpret_cast<const f32x4*>(x + e);
    f32x4 v1 = *reinterpret_cast<const f32x4*>(x + e + 4);
    short8 o;
    #pragma unroll
    for (int u = 0; u < 4; ++u) { o[u] = f2bf(v0[u]); o[4 + u] = f2bf(v1[u]); }
    *reinterpret_cast<short8*>(xb + e) = o;
}

__global__ __launch_bounds__(256) void init_state_kernel(int* sync, int* hb_i) {
    int e = blockIdx.x * 256 + threadIdx.x;
    if (e < 8192) sync[e] = 0;
    if (e < 65536) hb_i[e] = 0;
}

extern "C" __global__ void __launch_bounds__(NTHREADS, 1)
lstm_persistent(const short* __restrict__ Wpk, const short* __restrict__ xb,
                short* __restrict__ hb, float* __restrict__ out,
                const float* __restrict__ bf_, const float* __restrict__ bi_,
                const float* __restrict__ bc_, const float* __restrict__ bo_,
                int* __restrict__ sync)
{
    __shared__ float xch[4][256];                 // per-wave gather scratch (no barrier needed)
    const int tid = threadIdx.x, w = tid >> 6, lane = tid & 63;
    const int wg = blockIdx.x;
    const int r = lane & 15, hi = lane >> 4;
    const int mt = w;                             // wave's 16-row batch tile

    // ---- weights -> REGISTERS, once (48 B-frags = 192 VGPRs); untouched by fences ----
    short8 breg[48];
    const short* wsrc = Wpk + (size_t)wg * (48 * 64 * 8);
    #pragma unroll
    for (int ks = 0; ks < 48; ++ks)
        breg[ks] = *reinterpret_cast<const short8*>(wsrc + ((size_t)ks * 64 + lane) * 8);

    // lane's output element: row = hi*4 + (r>>2), col = wg*4 + (lane&3)
    const int i_e = r >> 2, ecj = lane & 3;
    const int row_g = mt * 16 + hi * 4 + i_e;
    const int col_g = wg * 4 + ecj;
    const float bfv = bf_[col_g], biv = bi_[col_g], bcv = bc_[col_g], bov = bo_[col_g];
    float creg = 0.f;

    int* root  = sync;
    int* grpc  = sync + 128  + (wg & 15) * 64;
    int* mymir = sync + 2048 + (wg & 15) * 64;

    f32x4 acc[4];
    #pragma unroll
    for (int c = 0; c < 4; ++c) acc[c] = (f32x4){0.f, 0.f, 0.f, 0.f};

    // prologue: x-part of step 0 (ksteps 32..47; independent of h)
    {
        short8 ax[16];
        #pragma unroll
        for (int s = 0; s < 16; ++s)
            ax[s] = *reinterpret_cast<const short8*>(xb + (size_t)(mt * 16 + r) * IN_DIM + s * 32 + hi * 8);
        #pragma unroll
        for (int s = 0; s < 16; ++s) acc[s & 3] = bmfma(ax[s], breg[32 + s], acc[s & 3]);
    }

    for (int t = 0; t < T_STEPS; ++t) {
        // ---- wait: h(t) published ----
        if (t > 0) {
            if (tid == 0) {
                while (__hip_atomic_load(mymir, __ATOMIC_RELAXED, __HIP_MEMORY_SCOPE_AGENT) < t)
                    __builtin_amdgcn_s_sleep(1);
            }
            __syncthreads();
            __builtin_amdgcn_fence(__ATOMIC_ACQUIRE, "agent");  // flash-inv: h refills fresh from L3
        }

        // ---- h-part: 32 ksteps, all A-frags prefetched in one volley ----
        const short* hcur = hb + (size_t)(t & 1) * (BATCH * H_DIM);
        short8 ah[32];
        #pragma unroll
        for (int s = 0; s < 32; ++s)
            ah[s] = *reinterpret_cast<const short8*>(hcur + (size_t)(mt * 16 + r) * H_DIM + s * 32 + hi * 8);
        #pragma unroll
        for (int s = 0; s < 32; ++s) acc[s & 3] = bmfma(ah[s], breg[s], acc[s & 3]);

        // ---- in-wave gate gather via LDS (write -> lgkmcnt(0) -> read; no barrier) ----
        f32x4 z4 = (acc[0] + acc[1]) + (acc[2] + acc[3]);
        float* wbase = &xch[w][0];
        *reinterpret_cast<f32x4*>(wbase + lane * 4) = z4;      // z[col=lane&15][row=hi*4+i]
        asm volatile("s_waitcnt lgkmcnt(0)" ::: "memory");
        __builtin_amdgcn_sched_barrier(0);
        const int gb = hi * 64 + ecj * 4 + i_e;                // + g*16 selects gate
        float zf = wbase[gb]      + bfv;
        float zi = wbase[gb + 16] + biv;
        float zc = wbase[gb + 32] + bcv;
        float zo = wbase[gb + 48] + bov;
        float fg  = 1.f / (1.f + __expf(-zf));
        float ig  = 1.f / (1.f + __expf(-zi));
        float cg_ = 2.f / (1.f + __expf(-2.f * zc)) - 1.f;
        float og  = 1.f / (1.f + __expf(-zo));
        creg = fg * creg + ig * cg_;
        float nh = og * (2.f / (1.f + __expf(-2.f * creg)) - 1.f);

        // ---- publish h via write-through agent stores (straight to L3; no wbl2 fence) ----
        unsigned mybits = (unsigned)(unsigned short)f2bf(nh);
        unsigned pbits  = __shfl_xor(mybits, 1);               // partner col (ecj^1), same row
        short* hnext = hb + (size_t)((t + 1) & 1) * (BATCH * H_DIM);
        if ((lane & 1) == 0) {
            unsigned val = mybits | (pbits << 16);
            __hip_atomic_store(reinterpret_cast<unsigned*>(hnext + (size_t)row_g * H_DIM + col_g),
                               val, __ATOMIC_RELAXED, __HIP_MEMORY_SCOPE_AGENT);
        }
        __builtin_nontemporal_store(nh, out + (size_t)t * (BATCH * H_DIM) + (size_t)row_g * H_DIM + col_g);

        // ---- arrive: stores drained by syncthreads, then 2-level RMW tree + mirror publish ----
        __syncthreads();
        if (tid == 0) {
            int old = __hip_atomic_fetch_add(grpc, 1, __ATOMIC_RELAXED, __HIP_MEMORY_SCOPE_AGENT);
            if (old == 16 * (t + 1) - 1) {
                int o2 = __hip_atomic_fetch_add(root, 1, __ATOMIC_RELAXED, __HIP_MEMORY_SCOPE_AGENT);
                if (o2 == 16 * (t + 1) - 1) {
                    #pragma unroll
                    for (int m = 0; m < 16; ++m)
                        __hip_atomic_store(sync + 2048 + m * 64, t + 1,
                                           __ATOMIC_RELAXED, __HIP_MEMORY_SCOPE_AGENT);
                }
            }
        }

        // ---- overlap: x-part of step t+1 in the barrier shadow ----
        #pragma unroll
        for (int c = 0; c < 4; ++c) acc[c] = (f32x4){0.f, 0.f, 0.f, 0.f};
        if (t + 1 < T_STEPS) {
            const short* xt = xb + (size_t)(t + 1) * (BATCH * IN_DIM);
            short8 ax[16];
            #pragma unroll
            for (int s = 0; s < 16; ++s)
                ax[s] = *reinterpret_cast<const short8*>(xt + (size_t)(mt * 16 + r) * IN_DIM + s * 32 + hi * 8);
            #pragma unroll
            for (int s = 0; s < 16; ++s) acc[s & 3] = bmfma(ax[s], breg[32 + s], acc[s & 3]);
        }
    }
}

extern "C" void kernel_launch(void* const* d_in, const int* in_sizes, int n_in,
                              void* d_out, int out_size, void* d_ws, size_t ws_size,
                              hipStream_t stream) {
    const float* x   = (const float*)d_in[0];
    const float* Wf  = (const float*)d_in[1];
    const float* Wi  = (const float*)d_in[2];
    const float* Wc  = (const float*)d_in[3];
    const float* Wo  = (const float*)d_in[4];
    const float* bf_ = (const float*)d_in[5];
    const float* bi_ = (const float*)d_in[6];
    const float* bc_ = (const float*)d_in[7];
    const float* bo_ = (const float*)d_in[8];
    float* out = (float*)d_out;

    char*  ws    = (char*)d_ws;
    int*   syncp = (int*)(ws + WS_SYNC);
    short* hbuf  = (short*)(ws + WS_HB);
    short* xb    = (short*)(ws + WS_XB);
    short* Wpk   = (short*)(ws + WS_WPK);

    const float* Ws[4] = {Wf, Wi, Wc, Wo};
    for (int g = 0; g < 4; ++g)
        pack_w_kernel<<<(H_DIM * KDIM) / 256, 256, 0, stream>>>(Ws[g], Wpk, g);
    xconv_kernel<<<(T_STEPS * BATCH * IN_DIM) / (256 * 8), 256, 0, stream>>>(x, xb);
    init_state_kernel<<<256, 256, 0, stream>>>(syncp, (int*)hbuf);

    const short* Wpk_c = Wpk; const short* xb_c = xb;
    void* args[] = {(void*)&Wpk_c, (void*)&xb_c, (void*)&hbuf, (void*)&out,
                    (void*)&bf_, (void*)&bi_, (void*)&bc_, (void*)&bo_, (void*)&syncp};
    hipLaunchCooperativeKernel((const void*)lstm_persistent, dim3(NWG), dim3(NTHREADS),
                               args, 0, stream);
}

// Round 8
// 6940.623 us; speedup vs baseline: 1.6660x; 1.0507x over previous
//
#include <hip/hip_runtime.h>
#include <hip/hip_bf16.h>
#include <stdint.h>

#define T_STEPS 512
#define BATCH   64
#define IN_DIM  512
#define H_DIM   1024
#define KDIM    1536
#define NWG     256
#define NTHREADS 256

// ws layout (bytes). sync ints: root@0, grpc[g]@128+64g (g<16), mirror[m]@2048+64m (m<16)
#define WS_SYNC 0
#define WS_HB   32768           // ping-pong h, 2*64*1024 bf16 = 262144 B
#define WS_XB   294912          // x as bf16 = 33554432 B
#define WS_WPK  33849344        // packed weights 12582912 B

typedef float  f32x4  __attribute__((ext_vector_type(4)));
typedef short  short8 __attribute__((ext_vector_type(8)));
typedef __bf16 bf16x8 __attribute__((ext_vector_type(8)));

__device__ __forceinline__ short f2bf(float f) {
    union { float f; unsigned u; } x; x.f = f;
    unsigned r = (x.u + 0x7fffu + ((x.u >> 16) & 1u)) >> 16;
    return (short)r;
}
__device__ __forceinline__ f32x4 bmfma(short8 a, short8 b, f32x4 c) {
    return __builtin_amdgcn_mfma_f32_16x16x32_bf16(
        __builtin_bit_cast(bf16x8, a), __builtin_bit_cast(bf16x8, b), c, 0, 0, 0);
}

// W[g] fp32 [1024][1536] -> per-WG(4 h-cols) B-frag order (unchanged, passed R7):
// Wpk[((wg*48+ks)*64 + h2*16 + (g*4+cj))*8 + u] = bf16(W[g][wg*4+cj][ks*32+h2*8+u])
__global__ __launch_bounds__(256) void pack_w_kernel(const float* __restrict__ W,
                                                     short* __restrict__ Wpk, int g) {
    int e = blockIdx.x * 256 + threadIdx.x;       // < 1024*1536
    int j = e / KDIM, k = e - j * KDIM;
    int wg = j >> 2, cj = j & 3, zc = g * 4 + cj;
    int ks = k >> 5, h2 = (k & 31) >> 3, u = k & 7;
    Wpk[(((size_t)(wg * 48 + ks) * 64) + h2 * 16 + zc) * 8 + u] = f2bf(W[e]);
}

__global__ __launch_bounds__(256) void xconv_kernel(const float* __restrict__ x,
                                                    short* __restrict__ xb) {
    size_t e = ((size_t)blockIdx.x * 256 + threadIdx.x) * 8;
    f32x4 v0 = *reinterpret_cast<const f32x4*>(x + e);
    f32x4 v1 = *reinterpret_cast<const f32x4*>(x + e + 4);
    short8 o;
    #pragma unroll
    for (int u = 0; u < 4; ++u) { o[u] = f2bf(v0[u]); o[4 + u] = f2bf(v1[u]); }
    *reinterpret_cast<short8*>(xb + e) = o;
}

__global__ __launch_bounds__(256) void init_state_kernel(int* sync, int* hb_i) {
    int e = blockIdx.x * 256 + threadIdx.x;
    if (e < 8192) sync[e] = 0;
    if (e < 65536) hb_i[e] = 0;
}

extern "C" __global__ void __launch_bounds__(NTHREADS, 1)
lstm_persistent(const short* __restrict__ Wpk, const short* __restrict__ xb,
                short* __restrict__ hb, float* __restrict__ out,
                const float* __restrict__ bf_, const float* __restrict__ bi_,
                const float* __restrict__ bc_, const float* __restrict__ bo_,
                int* __restrict__ sync)
{
    __shared__ short Wlds[48 * 64 * 8];           // 48 KB: B-frags, fence-immune
    __shared__ float xch[4][256];                 // per-wave gather scratch

    const int tid = threadIdx.x, w = tid >> 6, lane = tid & 63;
    const int wg = blockIdx.x;
    const int r = lane & 15, hi = lane >> 4;

    // ---- weights -> LDS, once ----
    const short* wsrc = Wpk + (size_t)wg * (48 * 64 * 8);
    #pragma unroll
    for (int q = 0; q < 12; ++q) {
        int sl = q * 256 + tid;                   // 3072 16B-slots
        *reinterpret_cast<short8*>(Wlds + sl * 8) =
            *reinterpret_cast<const short8*>(wsrc + (size_t)sl * 8);
    }

    // lane's output element: row = hi*4 + (r>>2), col = wg*4 + (lane&3)
    const int i_e = r >> 2, ecj = lane & 3;
    const int row_g = w * 16 + hi * 4 + i_e;
    const int col_g = wg * 4 + ecj;
    const float bfv = bf_[col_g], biv = bi_[col_g], bcv = bc_[col_g], bov = bo_[col_g];
    float creg = 0.f;

    int* root  = sync;
    int* grpc  = sync + 128  + (wg & 15) * 64;
    int* mymir = sync + 2048 + (wg & 15) * 64;
    __syncthreads();

    // ---- prologue: ax volley for t=0 (x never written -> fence-safe prefetch) ----
    short8 ax[16];
    #pragma unroll
    for (int s = 0; s < 16; ++s)
        ax[s] = *reinterpret_cast<const short8*>(xb + (size_t)(w * 16 + r) * IN_DIM + s * 32 + hi * 8);

    for (int t = 0; t < T_STEPS; ++t) {
        // ---- wait: h(t) published (t=0: zeros from init kernel) ----
        if (t > 0) {
            if (tid == 0) {
                while (__hip_atomic_load(mymir, __ATOMIC_RELAXED, __HIP_MEMORY_SCOPE_AGENT) < t)
                    __builtin_amdgcn_s_sleep(1);
            }
            __syncthreads();
            __builtin_amdgcn_fence(__ATOMIC_ACQUIRE, "agent");  // h refills fresh via L2
        }

        // ---- issue full ah volley first (one L3 latency, covered by x-MFMAs) ----
        const short* hcur = hb + (size_t)(t & 1) * (BATCH * H_DIM);
        short8 ah[32];
        #pragma unroll
        for (int s = 0; s < 32; ++s)
            ah[s] = *reinterpret_cast<const short8*>(hcur + (size_t)(w * 16 + r) * H_DIM + s * 32 + hi * 8);
        __builtin_amdgcn_sched_barrier(0);

        f32x4 acc[4];
        #pragma unroll
        for (int c = 0; c < 4; ++c) acc[c] = (f32x4){0.f, 0.f, 0.f, 0.f};

        // ---- x-part MFMAs: ax already in regs (prefetched last iteration) ----
        #pragma unroll
        for (int s = 0; s < 16; ++s) {
            short8 b = *reinterpret_cast<const short8*>(Wlds + ((size_t)(32 + s) * 64 + lane) * 8);
            acc[s & 3] = bmfma(ax[s], b, acc[s & 3]);
        }
        // ---- h-part MFMAs ----
        #pragma unroll
        for (int s = 0; s < 32; ++s) {
            short8 b = *reinterpret_cast<const short8*>(Wlds + ((size_t)s * 64 + lane) * 8);
            acc[s & 3] = bmfma(ah[s], b, acc[s & 3]);
        }

        // ---- in-wave gate gather via LDS (write -> lgkmcnt(0) -> read) ----
        f32x4 z4 = (acc[0] + acc[1]) + (acc[2] + acc[3]);
        float* wbase = &xch[w][0];
        *reinterpret_cast<f32x4*>(wbase + lane * 4) = z4;      // z[col=lane&15][row=hi*4+i]
        asm volatile("s_waitcnt lgkmcnt(0)" ::: "memory");
        __builtin_amdgcn_sched_barrier(0);
        const int gb = hi * 64 + ecj * 4 + i_e;
        float zf = wbase[gb]      + bfv;
        float zi = wbase[gb + 16] + biv;
        float zc = wbase[gb + 32] + bcv;
        float zo = wbase[gb + 48] + bov;
        float fg  = 1.f / (1.f + __expf(-zf));
        float ig  = 1.f / (1.f + __expf(-zi));
        float cg_ = 2.f / (1.f + __expf(-2.f * zc)) - 1.f;
        float og  = 1.f / (1.f + __expf(-zo));
        creg = fg * creg + ig * cg_;
        float nh = og * (2.f / (1.f + __expf(-2.f * creg)) - 1.f);

        // ---- publish h via write-through agent stores (no wbl2 fence needed) ----
        unsigned mybits = (unsigned)(unsigned short)f2bf(nh);
        unsigned pbits  = __shfl_xor(mybits, 1);               // partner col, same row
        short* hnext = hb + (size_t)((t + 1) & 1) * (BATCH * H_DIM);
        if ((lane & 1) == 0) {
            unsigned val = mybits | (pbits << 16);
            __hip_atomic_store(reinterpret_cast<unsigned*>(hnext + (size_t)row_g * H_DIM + col_g),
                               val, __ATOMIC_RELAXED, __HIP_MEMORY_SCOPE_AGENT);
        }
        __builtin_nontemporal_store(nh, out + (size_t)t * (BATCH * H_DIM) + (size_t)row_g * H_DIM + col_g);

        // ---- arrive: syncthreads drains stores, then 2-level tree + mirror publish ----
        __syncthreads();
        if (tid == 0) {
            int old = __hip_atomic_fetch_add(grpc, 1, __ATOMIC_RELAXED, __HIP_MEMORY_SCOPE_AGENT);
            if (old == 16 * (t + 1) - 1) {
                int o2 = __hip_atomic_fetch_add(root, 1, __ATOMIC_RELAXED, __HIP_MEMORY_SCOPE_AGENT);
                if (o2 == 16 * (t + 1) - 1) {
                    #pragma unroll
                    for (int m = 0; m < 16; ++m)
                        __hip_atomic_store(sync + 2048 + m * 64, t + 1,
                                           __ATOMIC_RELAXED, __HIP_MEMORY_SCOPE_AGENT);
                }
            }
        }

        // ---- shadow: prefetch next step's ax volley while others arrive ----
        if (t + 1 < T_STEPS) {
            const short* xt = xb + (size_t)(t + 1) * (BATCH * IN_DIM);
            #pragma unroll
            for (int s = 0; s < 16; ++s)
                ax[s] = *reinterpret_cast<const short8*>(xt + (size_t)(w * 16 + r) * IN_DIM + s * 32 + hi * 8);
            __builtin_amdgcn_sched_barrier(0);
        }
    }
}

extern "C" void kernel_launch(void* const* d_in, const int* in_sizes, int n_in,
                              void* d_out, int out_size, void* d_ws, size_t ws_size,
                              hipStream_t stream) {
    const float* x   = (const float*)d_in[0];
    const float* Wf  = (const float*)d_in[1];
    const float* Wi  = (const float*)d_in[2];
    const float* Wc  = (const float*)d_in[3];
    const float* Wo  = (const float*)d_in[4];
    const float* bf_ = (const float*)d_in[5];
    const float* bi_ = (const float*)d_in[6];
    const float* bc_ = (const float*)d_in[7];
    const float* bo_ = (const float*)d_in[8];
    float* out = (float*)d_out;

    char*  ws    = (char*)d_ws;
    int*   syncp = (int*)(ws + WS_SYNC);
    short* hbuf  = (short*)(ws + WS_HB);
    short* xb    = (short*)(ws + WS_XB);
    short* Wpk   = (short*)(ws + WS_WPK);

    const float* Ws[4] = {Wf, Wi, Wc, Wo};
    for (int g = 0; g < 4; ++g)
        pack_w_kernel<<<(H_DIM * KDIM) / 256, 256, 0, stream>>>(Ws[g], Wpk, g);
    xconv_kernel<<<(T_STEPS * BATCH * IN_DIM) / (256 * 8), 256, 0, stream>>>(x, xb);
    init_state_kernel<<<256, 256, 0, stream>>>(syncp, (int*)hbuf);

    const short* Wpk_c = Wpk; const short* xb_c = xb;
    void* args[] = {(void*)&Wpk_c, (void*)&xb_c, (void*)&hbuf, (void*)&out,
                    (void*)&bf_, (void*)&bi_, (void*)&bc_, (void*)&bo_, (void*)&syncp};
    hipLaunchCooperativeKernel((const void*)lstm_persistent, dim3(NWG), dim3(NTHREADS),
                               args, 0, stream);
}

// Round 10
// 2542.792 us; speedup vs baseline: 4.5474x; 2.7295x over previous
//
#include <hip/hip_runtime.h>
#include <hip/hip_bf16.h>
#include <stdint.h>

#define T_STEPS 512
#define BATCH   64
#define IN_DIM  512
#define H_DIM   1024
#define KDIM    1536
#define NWG     256
#define NTHREADS 256

// LDS layout (bytes)
#define WLDS_OFF 0
#define WLDS_BYTES (24*4*64*16)       // 98304: ksteps 0..23, 4 gates
#define HA_OFF   98304                // 32768: staged h tile (swizzled)
#define XA_OFF   131072               // 16384: staged x tile (swizzled)
#define SMZ_OFF  147456               // 16*65*4 = 4160
#define LDS_TOTAL 151616

// ws layout (bytes). sync ints: root@0, grpc[g]@128+64g (g<16), mirror[m]@2048+64m (m<16)
#define WS_SYNC 0
#define WS_HB   32768           // ping-pong h, 2*64*1024 bf16 = 262144 B
#define WS_XB   294912          // x as bf16 = 33554432 B
#define WS_WPK  33849344        // packed weights 12582912 B

typedef float  f32x4  __attribute__((ext_vector_type(4)));
typedef short  short8 __attribute__((ext_vector_type(8)));
typedef int    int4v  __attribute__((ext_vector_type(4)));
typedef __bf16 bf16x8 __attribute__((ext_vector_type(8)));

__device__ __forceinline__ short f2bf(float f) {
    union { float f; unsigned u; } x; x.f = f;
    unsigned r = (x.u + 0x7fffu + ((x.u >> 16) & 1u)) >> 16;
    return (short)r;
}
__device__ __forceinline__ f32x4 bmfma(short8 a, short8 b, f32x4 c) {
    return __builtin_amdgcn_mfma_f32_16x16x32_bf16(
        __builtin_bit_cast(bf16x8, a), __builtin_bit_cast(bf16x8, b), c, 0, 0, 0);
}

// W[g] fp32 [1024][1536] -> B-frag order per 16-col group (unchanged from R9):
// Wpk[(((cb*48+ks)*4+g)*64 + grp*16+n)*8 + u] = bf16(W[g][cb*16+n][ks*32+grp*8+u])
__global__ __launch_bounds__(256) void pack_w_kernel(const float* __restrict__ W,
                                                     short* __restrict__ Wpk, int g) {
    int e = blockIdx.x * 256 + threadIdx.x;       // < 1024*1536
    int j = e / KDIM, k = e - j * KDIM;
    int cb = j >> 4, n = j & 15;
    int ks = k >> 5, grp = (k & 31) >> 3, u = k & 7;
    size_t dst = (((size_t)(cb * 48 + ks) * 4 + g) * 64 + grp * 16 + n) * 8 + u;
    Wpk[dst] = f2bf(W[e]);
}

__global__ __launch_bounds__(256) void xconv_kernel(const float* __restrict__ x,
                                                    short* __restrict__ xb) {
    size_t e = ((size_t)blockIdx.x * 256 + threadIdx.x) * 8;
    f32x4 v0 = *reinterpret_cast<const f32x4*>(x + e);
    f32x4 v1 = *reinterpret_cast<const f32x4*>(x + e + 4);
    short8 o;
    #pragma unroll
    for (int u = 0; u < 4; ++u) { o[u] = f2bf(v0[u]); o[4 + u] = f2bf(v1[u]); }
    *reinterpret_cast<short8*>(xb + e) = o;
}

__global__ __launch_bounds__(256) void init_state_kernel(int* sync, int* hb_i) {
    int e = blockIdx.x * 256 + threadIdx.x;
    if (e < 8192) sync[e] = 0;
    if (e < 65536) hb_i[e] = 0;                   // both h ping-pong buffers
}

extern "C" __global__ void __launch_bounds__(NTHREADS, 1)
lstm_persistent(const short* __restrict__ Wpk, const short* __restrict__ xb,
                short* __restrict__ hb, float* __restrict__ out,
                const float* __restrict__ bf_, const float* __restrict__ bi_,
                const float* __restrict__ bc_, const float* __restrict__ bo_,
                int* __restrict__ sync)
{
    extern __shared__ char lds[];
    short* Wlds = (short*)(lds + WLDS_OFF);       // [24][4][64][8]
    short* hA   = (short*)(lds + HA_OFF);         // 16 rows x 128 16B-slots (swizzled)
    short* xA   = (short*)(lds + XA_OFF);         // 16 rows x 64 16B-slots (swizzled)
    float* smZ  = (float*)(lds + SMZ_OFF);        // [16][65]

    const int tid = threadIdx.x, w = tid >> 6, lane = tid & 63;
    const int wg = blockIdx.x;
    const int bt = wg >> 6, cb = wg & 63;         // wg = cb + 64*bt
    const int r = lane & 15, hi = lane >> 4;

    const int erow = tid >> 4, ecol = tid & 15;
    const int row_g = bt * 16 + erow, col_g = cb * 16 + ecol;
    const float bfv = bf_[col_g], biv = bi_[col_g], bcv = bc_[col_g], bov = bo_[col_g];
    float creg = 0.f;

    int* root  = sync;
    int* grpc  = sync + 128  + (wg & 15) * 64;
    int* mymir = sync + 2048 + (wg & 15) * 64;

    // ---- stage weight ksteps 0..23 into LDS once (96 KB contiguous copy) ----
    const short* wgrp = Wpk + (size_t)cb * (48 * 4 * 64 * 8);
    #pragma unroll
    for (int q = 0; q < 24; ++q) {
        int sl = q * 256 + tid;                   // < 6144 16B-slots
        *reinterpret_cast<short8*>(Wlds + sl * 8) =
            *reinterpret_cast<const short8*>(wgrp + (size_t)sl * 8);
    }
    // streamed-B base for this wave's gate (ksteps 24..47, from warm L2 — no fences ever)
    const short* wstream = wgrp + (((size_t)24 * 4 + w) * 64 + lane) * 8;

    // ---- stage x(0): plain loads, swizzled source -> linear LDS ----
    {
        const short* xt = xb + ((size_t)0 * BATCH + bt * 16) * IN_DIM;
        #pragma unroll
        for (int q = 0; q < 4; ++q) {
            int slot = q * 256 + tid, rr = slot >> 6, idx = slot & 63;
            short8 v = *reinterpret_cast<const short8*>(xt + rr * IN_DIM + ((idx ^ (rr & 7)) << 3));
            *reinterpret_cast<short8*>(&xA[slot * 8]) = v;
        }
    }

    for (int t = 0; t < T_STEPS; ++t) {
        // ---- detect h(t) published (t=0: zeros from init) ----
        if (t > 0) {
            if (tid == 0) {
                while (__hip_atomic_load(mymir, __ATOMIC_RELAXED, __HIP_MEMORY_SCOPE_AGENT) < t)
                    __builtin_amdgcn_s_sleep(1);
            }
        }
        __syncthreads();                          // also orders Wlds/xA/hA stage writes

        // ---- h-stage: coherent agent-scope atomic 8B loads (the PROVEN primitive;
        //      same encoding the mirror poll uses) -> swizzled LDS. No fence. ----
        const short* hcur = hb + (size_t)(t & 1) * (BATCH * H_DIM);
        #pragma unroll
        for (int q = 0; q < 8; ++q) {
            int slot = q * 256 + tid, rr = slot >> 7, idx = slot & 127;
            const unsigned long long* src = reinterpret_cast<const unsigned long long*>(
                hcur + ((bt * 16 + rr) << 10) + ((idx ^ (rr & 7)) << 3));
            unsigned long long lo = __hip_atomic_load(src,     __ATOMIC_RELAXED, __HIP_MEMORY_SCOPE_AGENT);
            unsigned long long hi8 = __hip_atomic_load(src + 1, __ATOMIC_RELAXED, __HIP_MEMORY_SCOPE_AGENT);
            unsigned long long* dst = reinterpret_cast<unsigned long long*>(&hA[slot * 8]);
            dst[0] = lo; dst[1] = hi8;
        }
        __syncthreads();

        // ---- compute: A from LDS (swizzled); B: ks<24 LDS, ks>=24 warm-L2 stream ----
        f32x4 acc[4];
        #pragma unroll
        for (int c = 0; c < 4; ++c) acc[c] = (f32x4){0.f, 0.f, 0.f, 0.f};
        #pragma unroll
        for (int ks = 0; ks < 24; ++ks) {
            short8 a = *reinterpret_cast<const short8*>(&hA[r * 1024 + (((ks * 4 + hi) ^ (r & 7)) << 3)]);
            short8 b = *reinterpret_cast<const short8*>(Wlds + ((size_t)(ks * 4 + w) * 64 + lane) * 8);
            acc[ks & 3] = bmfma(a, b, acc[ks & 3]);
        }
        #pragma unroll
        for (int ks = 24; ks < 32; ++ks) {
            short8 a = *reinterpret_cast<const short8*>(&hA[r * 1024 + (((ks * 4 + hi) ^ (r & 7)) << 3)]);
            short8 b = *reinterpret_cast<const short8*>(wstream + (size_t)(ks - 24) * 2048);
            acc[ks & 3] = bmfma(a, b, acc[ks & 3]);
        }
        #pragma unroll
        for (int ksx = 0; ksx < 16; ++ksx) {
            short8 a = *reinterpret_cast<const short8*>(&xA[r * 512 + (((ksx * 4 + hi) ^ (r & 7)) << 3)]);
            short8 b = *reinterpret_cast<const short8*>(wstream + (size_t)(8 + ksx) * 2048);
            acc[ksx & 3] = bmfma(a, b, acc[ksx & 3]);
        }

        // ---- gather z across waves (wave w = gate w) ----
        f32x4 z4 = (acc[0] + acc[1]) + (acc[2] + acc[3]);
        #pragma unroll
        for (int i = 0; i < 4; ++i)               // C layout: col=lane&15, row=hi*4+i
            smZ[(hi * 4 + i) * 65 + w * 16 + r] = z4[i];
        __syncthreads();

        float zf = smZ[erow * 65 + ecol]      + bfv;
        float zi = smZ[erow * 65 + 16 + ecol] + biv;
        float zc = smZ[erow * 65 + 32 + ecol] + bcv;
        float zo = smZ[erow * 65 + 48 + ecol] + bov;
        float fg  = 1.f / (1.f + __expf(-zf));
        float ig  = 1.f / (1.f + __expf(-zi));
        float cg_ = 2.f / (1.f + __expf(-2.f * zc)) - 1.f;
        float og  = 1.f / (1.f + __expf(-zo));
        creg = fg * creg + ig * cg_;
        float nh = og * (2.f / (1.f + __expf(-2.f * creg)) - 1.f);

        // ---- publish h (write-through agent stores, proven R7/R8) + out (NT) ----
        unsigned mybits = (unsigned)(unsigned short)f2bf(nh);
        unsigned pbits  = __shfl_xor(mybits, 1);  // partner col (ecol^1), same row
        short* hnext = hb + (size_t)((t + 1) & 1) * (BATCH * H_DIM);
        if ((tid & 1) == 0) {
            unsigned val = mybits | (pbits << 16);
            __hip_atomic_store(reinterpret_cast<unsigned*>(hnext + (size_t)row_g * H_DIM + col_g),
                               val, __ATOMIC_RELAXED, __HIP_MEMORY_SCOPE_AGENT);
        }
        __builtin_nontemporal_store(nh, out + (size_t)t * (BATCH * H_DIM) + (size_t)row_g * H_DIM + col_g);

        // ---- arrive: drain stores, 2-level RMW tree, mirror publish ----
        __syncthreads();
        if (tid == 0) {
            int old = __hip_atomic_fetch_add(grpc, 1, __ATOMIC_RELAXED, __HIP_MEMORY_SCOPE_AGENT);
            if (old == 16 * (t + 1) - 1) {
                int o2 = __hip_atomic_fetch_add(root, 1, __ATOMIC_RELAXED, __HIP_MEMORY_SCOPE_AGENT);
                if (o2 == 16 * (t + 1) - 1) {
                    #pragma unroll
                    for (int m = 0; m < 16; ++m)
                        __hip_atomic_store(sync + 2048 + m * 64, t + 1,
                                           __ATOMIC_RELAXED, __HIP_MEMORY_SCOPE_AGENT);
                }
            }
        }

        // ---- shadow: stage x(t+1) while others arrive ----
        if (t + 1 < T_STEPS) {
            const short* xt = xb + ((size_t)(t + 1) * BATCH + bt * 16) * IN_DIM;
            #pragma unroll
            for (int q = 0; q < 4; ++q) {
                int slot = q * 256 + tid, rr = slot >> 6, idx = slot & 63;
                short8 v = *reinterpret_cast<const short8*>(xt + rr * IN_DIM + ((idx ^ (rr & 7)) << 3));
                *reinterpret_cast<short8*>(&xA[slot * 8]) = v;
            }
        }
    }
}

extern "C" void kernel_launch(void* const* d_in, const int* in_sizes, int n_in,
                              void* d_out, int out_size, void* d_ws, size_t ws_size,
                              hipStream_t stream) {
    const float* x   = (const float*)d_in[0];
    const float* Wf  = (const float*)d_in[1];
    const float* Wi  = (const float*)d_in[2];
    const float* Wc  = (const float*)d_in[3];
    const float* Wo  = (const float*)d_in[4];
    const float* bf_ = (const float*)d_in[5];
    const float* bi_ = (const float*)d_in[6];
    const float* bc_ = (const float*)d_in[7];
    const float* bo_ = (const float*)d_in[8];
    float* out = (float*)d_out;

    char*  ws    = (char*)d_ws;
    int*   syncp = (int*)(ws + WS_SYNC);
    short* hbuf  = (short*)(ws + WS_HB);
    short* xb    = (short*)(ws + WS_XB);
    short* Wpk   = (short*)(ws + WS_WPK);

    hipFuncSetAttribute((const void*)lstm_persistent,
                        hipFuncAttributeMaxDynamicSharedMemorySize, LDS_TOTAL);

    const float* Ws[4] = {Wf, Wi, Wc, Wo};
    for (int g = 0; g < 4; ++g)
        pack_w_kernel<<<(H_DIM * KDIM) / 256, 256, 0, stream>>>(Ws[g], Wpk, g);
    xconv_kernel<<<(T_STEPS * BATCH * IN_DIM) / (256 * 8), 256, 0, stream>>>(x, xb);
    init_state_kernel<<<256, 256, 0, stream>>>(syncp, (int*)hbuf);

    const short* Wpk_c = Wpk; const short* xb_c = xb;
    void* args[] = {(void*)&Wpk_c, (void*)&xb_c, (void*)&hbuf, (void*)&out,
                    (void*)&bf_, (void*)&bi_, (void*)&bc_, (void*)&bo_, (void*)&syncp};
    hipLaunchCooperativeKernel((const void*)lstm_persistent, dim3(NWG), dim3(NTHREADS),
                               args, LDS_TOTAL, stream);
}